// Round 17
// baseline (405.414 us; speedup 1.0000x reference)
//
#include <hip/hip_runtime.h>
#include <hip/hip_bf16.h>

#define NF 100000
#define TM 64
#define NB 1563   // ceil(NF/TM)

typedef __attribute__((ext_vector_type(8))) short bf16x8;
typedef __attribute__((ext_vector_type(4))) short bf16x4;
typedef __attribute__((ext_vector_type(4))) float f32x4;

__device__ __forceinline__ short bfs(float x) {
    union { __hip_bfloat16 h; short s; } u;
    u.h = __float2bfloat16(x);
    return u.s;
}

__device__ __forceinline__ float b2f(short s) {
    union { float f; unsigned u; } u;
    u.u = ((unsigned)(unsigned short)s) << 16;
    return u.f;
}

__device__ __forceinline__ bf16x8 cvt8(const float4 a, const float4 b) {
    bf16x8 r;
    r[0] = bfs(a.x); r[1] = bfs(a.y); r[2] = bfs(a.z); r[3] = bfs(a.w);
    r[4] = bfs(b.x); r[5] = bfs(b.y); r[6] = bfs(b.z); r[7] = bfs(b.w);
    return r;
}

__device__ __forceinline__ float mish_f(float v) {
    float t = __expf(v);
    float p = t * (t + 2.0f);
    float r = v * p * __builtin_amdgcn_rcpf(p + 2.0f);
    return (v > 20.0f) ? v : r;
}

// ---- merged fp32->bf16 conversion: embeddings (linear) + weights (K-slab) ----
struct CvtA {
    const float* src[8];
    long pre[9];
    int  Dv[8];
    const float* emb;
    long embElems;
};

__global__ __launch_bounds__(256)
void cvt_all(CvtA a, __hip_bfloat16* __restrict__ dst) {
    long e = ((long)blockIdx.x * 256 + threadIdx.x) * 8;
    if (e < a.embElems) {
        const float4* s = (const float4*)(a.emb + e);
        *(bf16x8*)(dst + e) = cvt8(s[0], s[1]);
        return;
    }
    long we = e - a.embElems;
    if (we >= a.pre[8]) return;
    int j = 0;
    #pragma unroll
    for (int q = 0; q < 8; q++) if (we >= a.pre[q + 1]) j = q + 1;
    long le = we - a.pre[j];
    const int D = a.Dv[j];
    int g = (int)(le / ((long)D * D));
    int rem = (int)(le - (long)g * D * D);
    int n = rem / D;
    int k = rem - n * D;
    const float4* s = (const float4*)(a.src[j] + le);
    long off = a.embElems + a.pre[j] + (long)g * D * D + (long)(k >> 5) * 32 * D + n * 32 + (k & 31);
    *(bf16x8*)(dst + off) = cvt8(s[0], s[1]);
}

// ---- per-group body ----
// WMODE 0 (D<=128): full Wi/Wo preload in regs; SEPARATE X/H LDS regions ->
//                   only 2 barriers, residual read from intact X region.
// WMODE 1 (D==192): 1-slab-ahead weight double-buffer; residual re-read from emb.
// WMODE 2 (D==256): plain in-loop K-slab weight loads; residual re-read from emb.
template<int D, int A, int WMODE>
__device__ __forceinline__ void body(
    int fb, int g,
    const __hip_bfloat16* __restrict__ emb, const int* __restrict__ idx,
    const __hip_bfloat16* __restrict__ wi, const float* __restrict__ bi,
    const __hip_bfloat16* __restrict__ wo, const float* __restrict__ bo,
    float* __restrict__ out_msgs, float* __restrict__ out_idx,
    __hip_bfloat16* __restrict__ buf)
{
    constexpr int DP = D + 8;
    constexpr int CT = D / 64;
    constexpr int KS = D / 32;
    constexpr int RC = D / 8;
    constexpr int CH = (TM * RC) / 256;

    const int f0   = fb * TM;
    const int tid  = threadIdx.x;
    const int lane = tid & 63;
    const int w    = tid >> 6;
    const long gFA = (long)g * NF * A;
    const int valid = min(TM, NF - f0);
    const int* idx_g = idx + gFA + (long)f0 * A;

    const int ar = lane & 15;
    const int kg = lane >> 4;
    const int c0 = w * (D / 4);
    const long wlane = (long)g * D * D + (long)(c0 + ar) * 32 + kg * 8;

    __hip_bfloat16* X = buf;
    __hip_bfloat16* H = (WMODE == 0) ? buf + TM * DP : buf;

    // ---- gather with explicit MLP ----
    {
        int nodes[CH];
        #pragma unroll
        for (int j = 0; j < CH; j++) {
            int c = tid + j * 256;
            int r = c / RC;
            nodes[j] = (r < valid) ? idx_g[r * A + ((c % RC) >> 3)] : idx_g[0];
        }
        bf16x8 v[CH];
        #pragma unroll
        for (int j = 0; j < CH; j++) {
            int c = tid + j * 256;
            v[j] = *(const bf16x8*)(emb + (long)nodes[j] * 64 + (((c % RC) * 8) & 63));
        }
        #pragma unroll
        for (int j = 0; j < CH; j++) {
            int c = tid + j * 256;
            *(bf16x8*)(X + (c / RC) * DP + (c % RC) * 8) = v[j];
        }
        if (tid < valid * A)
            __builtin_nontemporal_store((float)idx_g[tid], &out_idx[gFA + (long)f0 * A + tid]);
    }

    f32x4 acc[4][CT];
    #pragma unroll
    for (int rt = 0; rt < 4; rt++)
        #pragma unroll
        for (int ct = 0; ct < CT; ct++) acc[rt][ct] = (f32x4)0.0f;

    if constexpr (WMODE == 0) {
        // ---- full Wi preload (retires across the barrier) ----
        bf16x8 wia[KS][CT];
        #pragma unroll
        for (int ks = 0; ks < KS; ks++)
            #pragma unroll
            for (int ct = 0; ct < CT; ct++)
                wia[ks][ct] = *(const bf16x8*)(wi + wlane + (long)ks * 32 * D + ct * 512);

        __syncthreads();   // barrier 1: X visible

        #pragma unroll
        for (int ks = 0; ks < KS; ks++) {
            const int kk = ks * 32;
            bf16x8 xb[4];
            #pragma unroll
            for (int rt = 0; rt < 4; rt++)
                xb[rt] = *(const bf16x8*)(X + (rt * 16 + ar) * DP + kk + kg * 8);
            __builtin_amdgcn_s_setprio(1);
            #pragma unroll
            for (int ct = 0; ct < CT; ct++)
                #pragma unroll
                for (int rt = 0; rt < 4; rt++)
                    acc[rt][ct] = __builtin_amdgcn_mfma_f32_16x16x32_bf16(wia[ks][ct], xb[rt], acc[rt][ct], 0, 0, 0);
            __builtin_amdgcn_s_setprio(0);
        }

        // ---- full Wo preload (hides under mish) ----
        bf16x8 woa[KS][CT];
        #pragma unroll
        for (int ks = 0; ks < KS; ks++)
            #pragma unroll
            for (int ct = 0; ct < CT; ct++)
                woa[ks][ct] = *(const bf16x8*)(wo + wlane + (long)ks * 32 * D + ct * 512);

        // ---- mish -> H region (no barrier needed: disjoint from X) ----
        #pragma unroll
        for (int ct = 0; ct < CT; ct++) {
            const int cb = c0 + ct * 16 + kg * 4;
            const float4 bi4 = *(const float4*)(bi + g * D + cb);
            #pragma unroll
            for (int rt = 0; rt < 4; rt++) {
                bf16x4 hv;
                hv[0] = bfs(mish_f(acc[rt][ct][0] + bi4.x));
                hv[1] = bfs(mish_f(acc[rt][ct][1] + bi4.y));
                hv[2] = bfs(mish_f(acc[rt][ct][2] + bi4.z));
                hv[3] = bfs(mish_f(acc[rt][ct][3] + bi4.w));
                *(bf16x4*)(H + (rt * 16 + ar) * DP + cb) = hv;
            }
        }
        __syncthreads();   // barrier 2: H visible

        #pragma unroll
        for (int rt = 0; rt < 4; rt++)
            #pragma unroll
            for (int ct = 0; ct < CT; ct++) acc[rt][ct] = (f32x4)0.0f;

        #pragma unroll
        for (int ks = 0; ks < KS; ks++) {
            const int kk = ks * 32;
            bf16x8 hb[4];
            #pragma unroll
            for (int rt = 0; rt < 4; rt++)
                hb[rt] = *(const bf16x8*)(H + (rt * 16 + ar) * DP + kk + kg * 8);
            __builtin_amdgcn_s_setprio(1);
            #pragma unroll
            for (int ct = 0; ct < CT; ct++)
                #pragma unroll
                for (int rt = 0; rt < 4; rt++)
                    acc[rt][ct] = __builtin_amdgcn_mfma_f32_16x16x32_bf16(woa[ks][ct], hb[rt], acc[rt][ct], 0, 0, 0);
            __builtin_amdgcn_s_setprio(0);
        }

        // ---- epilogue 2: residual straight from intact X region ----
        float* ob = out_msgs + (gFA + (long)f0 * A) * 64;
        #pragma unroll
        for (int ct = 0; ct < CT; ct++) {
            const int cb = c0 + ct * 16 + kg * 4;
            const float4 bo4 = *(const float4*)(bo + g * D + cb);
            #pragma unroll
            for (int rt = 0; rt < 4; rt++) {
                const int r = rt * 16 + ar;
                bf16x4 xv = *(const bf16x4*)(X + (rt * 16 + ar) * DP + cb);
                f32x4 o;
                o[0] = acc[rt][ct][0] + bo4.x + b2f(xv[0]);
                o[1] = acc[rt][ct][1] + bo4.y + b2f(xv[1]);
                o[2] = acc[rt][ct][2] + bo4.z + b2f(xv[2]);
                o[3] = acc[rt][ct][3] + bo4.w + b2f(xv[3]);
                if (r < valid)
                    __builtin_nontemporal_store(o, (f32x4*)(ob + (long)r * D + cb));
            }
        }
    } else {
        // ---- WMODE 1/2: single-buffer, 3 barriers ----
        bf16x8 wcur[CT];
        if constexpr (WMODE == 1) {
            #pragma unroll
            for (int ct = 0; ct < CT; ct++)
                wcur[ct] = *(const bf16x8*)(wi + wlane + ct * 512);
        }
        __syncthreads();

        #pragma unroll
        for (int ks = 0; ks < KS; ks++) {
            const int kk = ks * 32;
            bf16x8 xb[4];
            #pragma unroll
            for (int rt = 0; rt < 4; rt++)
                xb[rt] = *(const bf16x8*)(X + (rt * 16 + ar) * DP + kk + kg * 8);
            if constexpr (WMODE == 1) {
                bf16x8 wnx[CT];
                if (ks + 1 < KS)
                    #pragma unroll
                    for (int ct = 0; ct < CT; ct++)
                        wnx[ct] = *(const bf16x8*)(wi + wlane + (long)(ks + 1) * 32 * D + ct * 512);
                __builtin_amdgcn_s_setprio(1);
                #pragma unroll
                for (int ct = 0; ct < CT; ct++)
                    #pragma unroll
                    for (int rt = 0; rt < 4; rt++)
                        acc[rt][ct] = __builtin_amdgcn_mfma_f32_16x16x32_bf16(wcur[ct], xb[rt], acc[rt][ct], 0, 0, 0);
                __builtin_amdgcn_s_setprio(0);
                if (ks + 1 < KS)
                    #pragma unroll
                    for (int ct = 0; ct < CT; ct++) wcur[ct] = wnx[ct];
            } else {
                bf16x8 wf[CT];
                #pragma unroll
                for (int ct = 0; ct < CT; ct++)
                    wf[ct] = *(const bf16x8*)(wi + wlane + (long)ks * 32 * D + ct * 512);
                __builtin_amdgcn_s_setprio(1);
                #pragma unroll
                for (int ct = 0; ct < CT; ct++)
                    #pragma unroll
                    for (int rt = 0; rt < 4; rt++)
                        acc[rt][ct] = __builtin_amdgcn_mfma_f32_16x16x32_bf16(wf[ct], xb[rt], acc[rt][ct], 0, 0, 0);
                __builtin_amdgcn_s_setprio(0);
            }
        }

        __syncthreads();   // all X reads complete before H overwrites buf

        #pragma unroll
        for (int ct = 0; ct < CT; ct++) {
            const int cb = c0 + ct * 16 + kg * 4;
            const float4 bi4 = *(const float4*)(bi + g * D + cb);
            #pragma unroll
            for (int rt = 0; rt < 4; rt++) {
                bf16x4 hv;
                hv[0] = bfs(mish_f(acc[rt][ct][0] + bi4.x));
                hv[1] = bfs(mish_f(acc[rt][ct][1] + bi4.y));
                hv[2] = bfs(mish_f(acc[rt][ct][2] + bi4.z));
                hv[3] = bfs(mish_f(acc[rt][ct][3] + bi4.w));
                *(bf16x4*)(H + (rt * 16 + ar) * DP + cb) = hv;
            }
        }
        __syncthreads();

        #pragma unroll
        for (int rt = 0; rt < 4; rt++)
            #pragma unroll
            for (int ct = 0; ct < CT; ct++) acc[rt][ct] = (f32x4)0.0f;

        if constexpr (WMODE == 1) {
            #pragma unroll
            for (int ct = 0; ct < CT; ct++)
                wcur[ct] = *(const bf16x8*)(wo + wlane + ct * 512);
        }

        #pragma unroll
        for (int ks = 0; ks < KS; ks++) {
            const int kk = ks * 32;
            bf16x8 hb[4];
            #pragma unroll
            for (int rt = 0; rt < 4; rt++)
                hb[rt] = *(const bf16x8*)(H + (rt * 16 + ar) * DP + kk + kg * 8);
            if constexpr (WMODE == 1) {
                bf16x8 wnx[CT];
                if (ks + 1 < KS)
                    #pragma unroll
                    for (int ct = 0; ct < CT; ct++)
                        wnx[ct] = *(const bf16x8*)(wo + wlane + (long)(ks + 1) * 32 * D + ct * 512);
                __builtin_amdgcn_s_setprio(1);
                #pragma unroll
                for (int ct = 0; ct < CT; ct++)
                    #pragma unroll
                    for (int rt = 0; rt < 4; rt++)
                        acc[rt][ct] = __builtin_amdgcn_mfma_f32_16x16x32_bf16(wcur[ct], hb[rt], acc[rt][ct], 0, 0, 0);
                __builtin_amdgcn_s_setprio(0);
                if (ks + 1 < KS)
                    #pragma unroll
                    for (int ct = 0; ct < CT; ct++) wcur[ct] = wnx[ct];
            } else {
                bf16x8 wf[CT];
                #pragma unroll
                for (int ct = 0; ct < CT; ct++)
                    wf[ct] = *(const bf16x8*)(wo + wlane + (long)ks * 32 * D + ct * 512);
                __builtin_amdgcn_s_setprio(1);
                #pragma unroll
                for (int ct = 0; ct < CT; ct++)
                    #pragma unroll
                    for (int rt = 0; rt < 4; rt++)
                        acc[rt][ct] = __builtin_amdgcn_mfma_f32_16x16x32_bf16(wf[ct], hb[rt], acc[rt][ct], 0, 0, 0);
                __builtin_amdgcn_s_setprio(0);
            }
        }

        // ---- epilogue 2: residual re-read from emb (bit-identical bf16) ----
        float* ob = out_msgs + (gFA + (long)f0 * A) * 64;
        #pragma unroll
        for (int ct = 0; ct < CT; ct++) {
            const int cb = c0 + ct * 16 + kg * 4;
            const int sres = (c0 + ct * 16) >> 6;
            const float4 bo4 = *(const float4*)(bo + g * D + cb);
            #pragma unroll
            for (int rt = 0; rt < 4; rt++) {
                const int r = rt * 16 + ar;
                int node = idx_g[min(r, valid - 1) * A + sres];
                bf16x4 xv = *(const bf16x4*)(emb + (long)node * 64 + (cb & 63));
                f32x4 o;
                o[0] = acc[rt][ct][0] + bo4.x + b2f(xv[0]);
                o[1] = acc[rt][ct][1] + bo4.y + b2f(xv[1]);
                o[2] = acc[rt][ct][2] + bo4.z + b2f(xv[2]);
                o[3] = acc[rt][ct][3] + bo4.w + b2f(xv[3]);
                if (r < valid)
                    __builtin_nontemporal_store(o, (f32x4*)(ob + (long)r * D + cb));
            }
        }
    }
}

struct KArgs {
    const __hip_bfloat16* emb;
    const int* idx[4];
    const __hip_bfloat16* wi[4]; const float* bi[4];
    const __hip_bfloat16* wo[4]; const float* bo[4];
    float* om[4]; float* oi[4];
};

// Single merged kernel with 8-way group interleave: b = 8j+s, s selects group
// (counts per 8 = 1,2,3,2 exactly matching NB*(1,2,3,2) group sizes — bijective).
// Consecutive dispatch indices hit different groups -> each CU's co-resident
// blocks mix MFMA-heavy (D256) with gather-heavy (D64/128) phases (m114 overlap).
// LDS 34816B: D=256 single region (64x264x2) OR two D<=128 regions (2x64x136x2).
__global__ __launch_bounds__(256, 4)
void fused_kernel(KArgs a) {
    __shared__ __hip_bfloat16 buf[2 * TM * 136];
    const int b = blockIdx.x;
    const int j = b >> 3;
    const int s = b & 7;
    if (s == 0) {
        body<256, 4, 2>(j, 0, a.emb, a.idx[3], a.wi[3], a.bi[3], a.wo[3], a.bo[3], a.om[3], a.oi[3], buf);
    } else if (s <= 2) {
        body<192, 3, 1>(j, s - 1, a.emb, a.idx[2], a.wi[2], a.bi[2], a.wo[2], a.bo[2], a.om[2], a.oi[2], buf);
    } else if (s <= 5) {
        body<128, 2, 0>(j, s - 3, a.emb, a.idx[1], a.wi[1], a.bi[1], a.wo[1], a.bo[1], a.om[1], a.oi[1], buf);
    } else {
        body<64, 1, 0>(j, s - 6, a.emb, a.idx[0], a.wi[0], a.bi[0], a.wo[0], a.bo[0], a.om[0], a.oi[0], buf);
    }
}

// ---- fallback (ws too small): on-the-fly f32 path, row-major weights ----
template<int D, int A, int MINW>
__global__ __launch_bounds__(256, MINW)
void msg_kernel(const float* __restrict__ embv,
                const int* __restrict__ idx,
                const float* __restrict__ wiv, const float* __restrict__ bi,
                const float* __restrict__ wov, const float* __restrict__ bo,
                float* __restrict__ out_msgs, float* __restrict__ out_idx)
{
    constexpr int DP = D + 8;
    constexpr int CT = D / 64;
    constexpr int KS = D / 32;
    constexpr int RC = D / 8;
    __shared__ __hip_bfloat16 buf[TM][DP];

    const int g    = blockIdx.y;
    const int f0   = blockIdx.x * TM;
    const int tid  = threadIdx.x;
    const int lane = tid & 63;
    const int w    = tid >> 6;
    const long gFA = (long)g * NF * A;
    const int valid = min(TM, NF - f0);

    {
        const int* idx_g = idx + gFA + (long)f0 * A;
        #pragma unroll
        for (int c = tid; c < TM * RC; c += 256) {
            int r = c / RC;
            int i = (c - r * RC) * 8;
            bf16x8 v = (bf16x8)0;
            if (r < valid) {
                int node = idx_g[r * A + (i >> 6)];
                const float4* s = (const float4*)(embv + (long)node * 64 + (i & 63));
                v = cvt8(s[0], s[1]);
            }
            *(bf16x8*)(&buf[r][i]) = v;
        }
        if (tid < valid * A) out_idx[gFA + (long)f0 * A + tid] = (float)idx_g[tid];
    }
    __syncthreads();

    const int ar = lane & 15;
    const int kg = lane >> 4;
    const int c0 = w * (D / 4);
    const long wbase = (long)g * D * D;

    f32x4 acc[4][CT];
    #pragma unroll
    for (int rt = 0; rt < 4; rt++)
        #pragma unroll
        for (int ct = 0; ct < CT; ct++) acc[rt][ct] = (f32x4)0.0f;

    #pragma unroll
    for (int ks = 0; ks < KS; ks++) {
        const int kk = ks * 32;
        bf16x8 xb[4];
        #pragma unroll
        for (int rt = 0; rt < 4; rt++) xb[rt] = *(const bf16x8*)(&buf[rt * 16 + ar][kk + kg * 8]);
        #pragma unroll
        for (int ct = 0; ct < CT; ct++) {
            const float4* bp = (const float4*)(wiv + wbase + (long)(c0 + ct * 16 + ar) * D + kk + kg * 8);
            bf16x8 wf = cvt8(bp[0], bp[1]);
            #pragma unroll
            for (int rt = 0; rt < 4; rt++)
                acc[rt][ct] = __builtin_amdgcn_mfma_f32_16x16x32_bf16(wf, xb[rt], acc[rt][ct], 0, 0, 0);
        }
    }

    bf16x4 res[4][CT];
    #pragma unroll
    for (int ct = 0; ct < CT; ct++) {
        const int cb = c0 + ct * 16 + kg * 4;
        #pragma unroll
        for (int rt = 0; rt < 4; rt++)
            res[rt][ct] = *(const bf16x4*)(&buf[rt * 16 + ar][cb]);
    }
    __syncthreads();

    #pragma unroll
    for (int ct = 0; ct < CT; ct++) {
        const int cb = c0 + ct * 16 + kg * 4;
        const float4 bi4 = *(const float4*)(bi + g * D + cb);
        #pragma unroll
        for (int rt = 0; rt < 4; rt++) {
            bf16x4 hv;
            hv[0] = bfs(mish_f(acc[rt][ct][0] + bi4.x));
            hv[1] = bfs(mish_f(acc[rt][ct][1] + bi4.y));
            hv[2] = bfs(mish_f(acc[rt][ct][2] + bi4.z));
            hv[3] = bfs(mish_f(acc[rt][ct][3] + bi4.w));
            *(bf16x4*)(&buf[rt * 16 + ar][cb]) = hv;
        }
    }
    __syncthreads();

    #pragma unroll
    for (int rt = 0; rt < 4; rt++)
        #pragma unroll
        for (int ct = 0; ct < CT; ct++) acc[rt][ct] = (f32x4)0.0f;

    #pragma unroll
    for (int ks = 0; ks < KS; ks++) {
        const int kk = ks * 32;
        bf16x8 hb[4];
        #pragma unroll
        for (int rt = 0; rt < 4; rt++) hb[rt] = *(const bf16x8*)(&buf[rt * 16 + ar][kk + kg * 8]);
        #pragma unroll
        for (int ct = 0; ct < CT; ct++) {
            const float4* bp = (const float4*)(wov + wbase + (long)(c0 + ct * 16 + ar) * D + kk + kg * 8);
            bf16x8 wf = cvt8(bp[0], bp[1]);
            #pragma unroll
            for (int rt = 0; rt < 4; rt++)
                acc[rt][ct] = __builtin_amdgcn_mfma_f32_16x16x32_bf16(wf, hb[rt], acc[rt][ct], 0, 0, 0);
        }
    }

    {
        float* ob = out_msgs + (gFA + (long)f0 * A) * 64;
        #pragma unroll
        for (int ct = 0; ct < CT; ct++) {
            const int cb = c0 + ct * 16 + kg * 4;
            const float4 bo4 = *(const float4*)(bo + g * D + cb);
            #pragma unroll
            for (int rt = 0; rt < 4; rt++) {
                const int r = rt * 16 + ar;
                float4 o;
                o.x = acc[rt][ct][0] + bo4.x + b2f(res[rt][ct][0]);
                o.y = acc[rt][ct][1] + bo4.y + b2f(res[rt][ct][1]);
                o.z = acc[rt][ct][2] + bo4.z + b2f(res[rt][ct][2]);
                o.w = acc[rt][ct][3] + bo4.w + b2f(res[rt][ct][3]);
                if (r < valid) *(float4*)(ob + (long)r * D + cb) = o;
            }
        }
    }
}

extern "C" void kernel_launch(void* const* d_in, const int* in_sizes, int n_in,
                              void* d_out, int out_size, void* d_ws, size_t ws_size,
                              hipStream_t stream) {
    const float* emb_f = (const float*)d_in[0];
    const int Gs[4] = {2, 3, 2, 1};
    const int Ds[4] = {64, 128, 192, 256};

    const int*   idx_a[4];
    const float *wi_f[4], *bi_f[4], *wo_f[4], *bo_f[4];
    for (int k = 0; k < 4; k++) {
        idx_a[k] = (const int*)d_in[1 + 5 * k];
        wi_f[k]  = (const float*)d_in[2 + 5 * k];
        bi_f[k]  = (const float*)d_in[3 + 5 * k];
        wo_f[k]  = (const float*)d_in[4 + 5 * k];
        bo_f[k]  = (const float*)d_in[5 + 5 * k];
    }

    float* out = (float*)d_out;
    const long MSG_ELEMS = 115200000L;
    const long rowOff[4] = {0, 200000, 800000, 1400000};
    float* om[4]; float* oi[4];
    for (int k = 0; k < 4; k++) {
        om[k] = out + rowOff[k] * 64;
        oi[k] = out + MSG_ELEMS + rowOff[k];
    }

    const long EMB_ELEMS = 6400000L;
    long wPre[9]; wPre[0] = 0;
    int  wD[8];
    for (int k = 0; k < 4; k++) {
        long we = (long)Gs[k] * Ds[k] * Ds[k];
        wPre[2 * k + 1] = wPre[2 * k] + we;
        wPre[2 * k + 2] = wPre[2 * k + 1] + we;
        wD[2 * k] = Ds[k]; wD[2 * k + 1] = Ds[k];
    }
    const long NEED = (EMB_ELEMS + wPre[8]) * 2;

    if (ws_size >= (size_t)NEED) {
        __hip_bfloat16* emb_b = (__hip_bfloat16*)d_ws;
        __hip_bfloat16* w_b   = emb_b + EMB_ELEMS;

        CvtA ca;
        for (int k = 0; k < 4; k++) { ca.src[2 * k] = wi_f[k]; ca.src[2 * k + 1] = wo_f[k]; }
        for (int j = 0; j < 9; j++) ca.pre[j] = wPre[j];
        for (int j = 0; j < 8; j++) ca.Dv[j] = wD[j];
        ca.emb = emb_f;
        ca.embElems = EMB_ELEMS;
        long totChunks = (EMB_ELEMS + wPre[8]) / 8;
        cvt_all<<<dim3((totChunks + 255) / 256), dim3(256), 0, stream>>>(ca, emb_b);

        KArgs a;
        a.emb = emb_b;
        for (int k = 0; k < 4; k++) {
            a.idx[k] = idx_a[k];
            a.wi[k] = w_b + wPre[2 * k];
            a.wo[k] = w_b + wPre[2 * k + 1];
            a.bi[k] = bi_f[k];
            a.bo[k] = bo_f[k];
            a.om[k] = om[k];
            a.oi[k] = oi[k];
        }
        fused_kernel<<<dim3(NB * 8), dim3(256), 0, stream>>>(a);
    } else {
        msg_kernel<64, 1, 4><<<dim3(NB, 2), 256, 0, stream>>>(
            emb_f, idx_a[0], wi_f[0], bi_f[0], wo_f[0], bo_f[0], om[0], oi[0]);
        msg_kernel<128, 2, 4><<<dim3(NB, 3), 256, 0, stream>>>(
            emb_f, idx_a[1], wi_f[1], bi_f[1], wo_f[1], bo_f[1], om[1], oi[1]);
        msg_kernel<192, 3, 4><<<dim3(NB, 2), 256, 0, stream>>>(
            emb_f, idx_a[2], wi_f[2], bi_f[2], wo_f[2], bo_f[2], om[2], oi[2]);
        msg_kernel<256, 4, 3><<<dim3(NB, 1), 256, 0, stream>>>(
            emb_f, idx_a[3], wi_f[3], bi_f[3], wo_f[3], bo_f[3], om[3], oi[3]);
    }
}

// Round 18
// 198.873 us; speedup vs baseline: 2.0386x; 2.0386x over previous
//
#include <hip/hip_runtime.h>
#include <hip/hip_bf16.h>

#define NF 100000
#define TM 64
#define NB 1563   // ceil(NF/TM)

typedef __attribute__((ext_vector_type(8))) short bf16x8;
typedef __attribute__((ext_vector_type(4))) short bf16x4;
typedef __attribute__((ext_vector_type(4))) float f32x4;

__device__ __forceinline__ short bfs(float x) {
    union { __hip_bfloat16 h; short s; } u;
    u.h = __float2bfloat16(x);
    return u.s;
}

__device__ __forceinline__ float b2f(short s) {
    union { float f; unsigned u; } u;
    u.u = ((unsigned)(unsigned short)s) << 16;
    return u.f;
}

__device__ __forceinline__ bf16x8 cvt8(const float4 a, const float4 b) {
    bf16x8 r;
    r[0] = bfs(a.x); r[1] = bfs(a.y); r[2] = bfs(a.z); r[3] = bfs(a.w);
    r[4] = bfs(b.x); r[5] = bfs(b.y); r[6] = bfs(b.z); r[7] = bfs(b.w);
    return r;
}

__device__ __forceinline__ float mish_f(float v) {
    float t = __expf(v);
    float p = t * (t + 2.0f);
    float r = v * p * __builtin_amdgcn_rcpf(p + 2.0f);
    return (v > 20.0f) ? v : r;
}

// ---- merged fp32->bf16 conversion: embeddings (linear) + weights (K-slab) ----
struct CvtA {
    const float* src[8];
    long pre[9];
    int  Dv[8];
    const float* emb;
    long embElems;
};

__global__ __launch_bounds__(256)
void cvt_all(CvtA a, __hip_bfloat16* __restrict__ dst) {
    long e = ((long)blockIdx.x * 256 + threadIdx.x) * 8;
    if (e < a.embElems) {
        const float4* s = (const float4*)(a.emb + e);
        *(bf16x8*)(dst + e) = cvt8(s[0], s[1]);
        return;
    }
    long we = e - a.embElems;
    if (we >= a.pre[8]) return;
    int j = 0;
    #pragma unroll
    for (int q = 0; q < 8; q++) if (we >= a.pre[q + 1]) j = q + 1;
    long le = we - a.pre[j];
    const int D = a.Dv[j];
    int g = (int)(le / ((long)D * D));
    int rem = (int)(le - (long)g * D * D);
    int n = rem / D;
    int k = rem - n * D;
    const float4* s = (const float4*)(a.src[j] + le);
    long off = a.embElems + a.pre[j] + (long)g * D * D + (long)(k >> 5) * 32 * D + n * 32 + (k & 31);
    *(bf16x8*)(dst + off) = cvt8(s[0], s[1]);
}

// ---- per-group body ----
// WMODE 0 (D<=128): full Wi/Wo preload in regs; SEPARATE X/H LDS regions ->
//                   only 2 barriers, residual read from intact X region.
// WMODE 1 (D==192): 1-slab-ahead weight double-buffer; residual re-read from emb.
// WMODE 2 (D==256): plain in-loop K-slab weight loads; residual re-read from emb.
template<int D, int A, int WMODE>
__device__ __forceinline__ void body(
    int fb, int g,
    const __hip_bfloat16* __restrict__ emb, const int* __restrict__ idx,
    const __hip_bfloat16* __restrict__ wi, const float* __restrict__ bi,
    const __hip_bfloat16* __restrict__ wo, const float* __restrict__ bo,
    float* __restrict__ out_msgs, float* __restrict__ out_idx,
    __hip_bfloat16* __restrict__ buf)
{
    constexpr int DP = D + 8;
    constexpr int CT = D / 64;
    constexpr int KS = D / 32;
    constexpr int RC = D / 8;
    constexpr int CH = (TM * RC) / 256;

    const int f0   = fb * TM;
    const int tid  = threadIdx.x;
    const int lane = tid & 63;
    const int w    = tid >> 6;
    const long gFA = (long)g * NF * A;
    const int valid = min(TM, NF - f0);
    const int* idx_g = idx + gFA + (long)f0 * A;

    const int ar = lane & 15;
    const int kg = lane >> 4;
    const int c0 = w * (D / 4);
    const long wlane = (long)g * D * D + (long)(c0 + ar) * 32 + kg * 8;

    __hip_bfloat16* X = buf;
    __hip_bfloat16* H = (WMODE == 0) ? buf + TM * DP : buf;

    // ---- gather with explicit MLP ----
    {
        int nodes[CH];
        #pragma unroll
        for (int j = 0; j < CH; j++) {
            int c = tid + j * 256;
            int r = c / RC;
            nodes[j] = (r < valid) ? idx_g[r * A + ((c % RC) >> 3)] : idx_g[0];
        }
        bf16x8 v[CH];
        #pragma unroll
        for (int j = 0; j < CH; j++) {
            int c = tid + j * 256;
            v[j] = *(const bf16x8*)(emb + (long)nodes[j] * 64 + (((c % RC) * 8) & 63));
        }
        #pragma unroll
        for (int j = 0; j < CH; j++) {
            int c = tid + j * 256;
            *(bf16x8*)(X + (c / RC) * DP + (c % RC) * 8) = v[j];
        }
        if (tid < valid * A)
            __builtin_nontemporal_store((float)idx_g[tid], &out_idx[gFA + (long)f0 * A + tid]);
    }

    f32x4 acc[4][CT];
    #pragma unroll
    for (int rt = 0; rt < 4; rt++)
        #pragma unroll
        for (int ct = 0; ct < CT; ct++) acc[rt][ct] = (f32x4)0.0f;

    if constexpr (WMODE == 0) {
        // ---- full Wi preload (retires across the barrier) ----
        bf16x8 wia[KS][CT];
        #pragma unroll
        for (int ks = 0; ks < KS; ks++)
            #pragma unroll
            for (int ct = 0; ct < CT; ct++)
                wia[ks][ct] = *(const bf16x8*)(wi + wlane + (long)ks * 32 * D + ct * 512);

        __syncthreads();   // barrier 1: X visible

        #pragma unroll
        for (int ks = 0; ks < KS; ks++) {
            const int kk = ks * 32;
            bf16x8 xb[4];
            #pragma unroll
            for (int rt = 0; rt < 4; rt++)
                xb[rt] = *(const bf16x8*)(X + (rt * 16 + ar) * DP + kk + kg * 8);
            __builtin_amdgcn_s_setprio(1);
            #pragma unroll
            for (int ct = 0; ct < CT; ct++)
                #pragma unroll
                for (int rt = 0; rt < 4; rt++)
                    acc[rt][ct] = __builtin_amdgcn_mfma_f32_16x16x32_bf16(wia[ks][ct], xb[rt], acc[rt][ct], 0, 0, 0);
            __builtin_amdgcn_s_setprio(0);
        }

        // ---- full Wo preload (hides under mish) ----
        bf16x8 woa[KS][CT];
        #pragma unroll
        for (int ks = 0; ks < KS; ks++)
            #pragma unroll
            for (int ct = 0; ct < CT; ct++)
                woa[ks][ct] = *(const bf16x8*)(wo + wlane + (long)ks * 32 * D + ct * 512);

        // ---- mish -> H region (no barrier needed: disjoint from X) ----
        #pragma unroll
        for (int ct = 0; ct < CT; ct++) {
            const int cb = c0 + ct * 16 + kg * 4;
            const float4 bi4 = *(const float4*)(bi + g * D + cb);
            #pragma unroll
            for (int rt = 0; rt < 4; rt++) {
                bf16x4 hv;
                hv[0] = bfs(mish_f(acc[rt][ct][0] + bi4.x));
                hv[1] = bfs(mish_f(acc[rt][ct][1] + bi4.y));
                hv[2] = bfs(mish_f(acc[rt][ct][2] + bi4.z));
                hv[3] = bfs(mish_f(acc[rt][ct][3] + bi4.w));
                *(bf16x4*)(H + (rt * 16 + ar) * DP + cb) = hv;
            }
        }
        __syncthreads();   // barrier 2: H visible

        #pragma unroll
        for (int rt = 0; rt < 4; rt++)
            #pragma unroll
            for (int ct = 0; ct < CT; ct++) acc[rt][ct] = (f32x4)0.0f;

        #pragma unroll
        for (int ks = 0; ks < KS; ks++) {
            const int kk = ks * 32;
            bf16x8 hb[4];
            #pragma unroll
            for (int rt = 0; rt < 4; rt++)
                hb[rt] = *(const bf16x8*)(H + (rt * 16 + ar) * DP + kk + kg * 8);
            __builtin_amdgcn_s_setprio(1);
            #pragma unroll
            for (int ct = 0; ct < CT; ct++)
                #pragma unroll
                for (int rt = 0; rt < 4; rt++)
                    acc[rt][ct] = __builtin_amdgcn_mfma_f32_16x16x32_bf16(woa[ks][ct], hb[rt], acc[rt][ct], 0, 0, 0);
            __builtin_amdgcn_s_setprio(0);
        }

        // ---- epilogue 2: residual straight from intact X region ----
        float* ob = out_msgs + (gFA + (long)f0 * A) * 64;
        #pragma unroll
        for (int ct = 0; ct < CT; ct++) {
            const int cb = c0 + ct * 16 + kg * 4;
            const float4 bo4 = *(const float4*)(bo + g * D + cb);
            #pragma unroll
            for (int rt = 0; rt < 4; rt++) {
                const int r = rt * 16 + ar;
                bf16x4 xv = *(const bf16x4*)(X + (rt * 16 + ar) * DP + cb);
                f32x4 o;
                o[0] = acc[rt][ct][0] + bo4.x + b2f(xv[0]);
                o[1] = acc[rt][ct][1] + bo4.y + b2f(xv[1]);
                o[2] = acc[rt][ct][2] + bo4.z + b2f(xv[2]);
                o[3] = acc[rt][ct][3] + bo4.w + b2f(xv[3]);
                if (r < valid)
                    __builtin_nontemporal_store(o, (f32x4*)(ob + (long)r * D + cb));
            }
        }
    } else {
        // ---- WMODE 1/2: single-buffer, 3 barriers ----
        bf16x8 wcur[CT];
        if constexpr (WMODE == 1) {
            #pragma unroll
            for (int ct = 0; ct < CT; ct++)
                wcur[ct] = *(const bf16x8*)(wi + wlane + ct * 512);
        }
        __syncthreads();

        #pragma unroll
        for (int ks = 0; ks < KS; ks++) {
            const int kk = ks * 32;
            bf16x8 xb[4];
            #pragma unroll
            for (int rt = 0; rt < 4; rt++)
                xb[rt] = *(const bf16x8*)(X + (rt * 16 + ar) * DP + kk + kg * 8);
            if constexpr (WMODE == 1) {
                bf16x8 wnx[CT];
                if (ks + 1 < KS)
                    #pragma unroll
                    for (int ct = 0; ct < CT; ct++)
                        wnx[ct] = *(const bf16x8*)(wi + wlane + (long)(ks + 1) * 32 * D + ct * 512);
                __builtin_amdgcn_s_setprio(1);
                #pragma unroll
                for (int ct = 0; ct < CT; ct++)
                    #pragma unroll
                    for (int rt = 0; rt < 4; rt++)
                        acc[rt][ct] = __builtin_amdgcn_mfma_f32_16x16x32_bf16(wcur[ct], xb[rt], acc[rt][ct], 0, 0, 0);
                __builtin_amdgcn_s_setprio(0);
                if (ks + 1 < KS)
                    #pragma unroll
                    for (int ct = 0; ct < CT; ct++) wcur[ct] = wnx[ct];
            } else {
                bf16x8 wf[CT];
                #pragma unroll
                for (int ct = 0; ct < CT; ct++)
                    wf[ct] = *(const bf16x8*)(wi + wlane + (long)ks * 32 * D + ct * 512);
                __builtin_amdgcn_s_setprio(1);
                #pragma unroll
                for (int ct = 0; ct < CT; ct++)
                    #pragma unroll
                    for (int rt = 0; rt < 4; rt++)
                        acc[rt][ct] = __builtin_amdgcn_mfma_f32_16x16x32_bf16(wf[ct], xb[rt], acc[rt][ct], 0, 0, 0);
                __builtin_amdgcn_s_setprio(0);
            }
        }

        __syncthreads();   // all X reads complete before H overwrites buf

        #pragma unroll
        for (int ct = 0; ct < CT; ct++) {
            const int cb = c0 + ct * 16 + kg * 4;
            const float4 bi4 = *(const float4*)(bi + g * D + cb);
            #pragma unroll
            for (int rt = 0; rt < 4; rt++) {
                bf16x4 hv;
                hv[0] = bfs(mish_f(acc[rt][ct][0] + bi4.x));
                hv[1] = bfs(mish_f(acc[rt][ct][1] + bi4.y));
                hv[2] = bfs(mish_f(acc[rt][ct][2] + bi4.z));
                hv[3] = bfs(mish_f(acc[rt][ct][3] + bi4.w));
                *(bf16x4*)(H + (rt * 16 + ar) * DP + cb) = hv;
            }
        }
        __syncthreads();

        #pragma unroll
        for (int rt = 0; rt < 4; rt++)
            #pragma unroll
            for (int ct = 0; ct < CT; ct++) acc[rt][ct] = (f32x4)0.0f;

        if constexpr (WMODE == 1) {
            #pragma unroll
            for (int ct = 0; ct < CT; ct++)
                wcur[ct] = *(const bf16x8*)(wo + wlane + ct * 512);
        }

        #pragma unroll
        for (int ks = 0; ks < KS; ks++) {
            const int kk = ks * 32;
            bf16x8 hb[4];
            #pragma unroll
            for (int rt = 0; rt < 4; rt++)
                hb[rt] = *(const bf16x8*)(H + (rt * 16 + ar) * DP + kk + kg * 8);
            if constexpr (WMODE == 1) {
                bf16x8 wnx[CT];
                if (ks + 1 < KS)
                    #pragma unroll
                    for (int ct = 0; ct < CT; ct++)
                        wnx[ct] = *(const bf16x8*)(wo + wlane + (long)(ks + 1) * 32 * D + ct * 512);
                __builtin_amdgcn_s_setprio(1);
                #pragma unroll
                for (int ct = 0; ct < CT; ct++)
                    #pragma unroll
                    for (int rt = 0; rt < 4; rt++)
                        acc[rt][ct] = __builtin_amdgcn_mfma_f32_16x16x32_bf16(wcur[ct], hb[rt], acc[rt][ct], 0, 0, 0);
                __builtin_amdgcn_s_setprio(0);
                if (ks + 1 < KS)
                    #pragma unroll
                    for (int ct = 0; ct < CT; ct++) wcur[ct] = wnx[ct];
            } else {
                bf16x8 wf[CT];
                #pragma unroll
                for (int ct = 0; ct < CT; ct++)
                    wf[ct] = *(const bf16x8*)(wo + wlane + (long)ks * 32 * D + ct * 512);
                __builtin_amdgcn_s_setprio(1);
                #pragma unroll
                for (int ct = 0; ct < CT; ct++)
                    #pragma unroll
                    for (int rt = 0; rt < 4; rt++)
                        acc[rt][ct] = __builtin_amdgcn_mfma_f32_16x16x32_bf16(wf[ct], hb[rt], acc[rt][ct], 0, 0, 0);
                __builtin_amdgcn_s_setprio(0);
            }
        }

        // ---- epilogue 2: residual re-read from emb (bit-identical bf16) ----
        float* ob = out_msgs + (gFA + (long)f0 * A) * 64;
        #pragma unroll
        for (int ct = 0; ct < CT; ct++) {
            const int cb = c0 + ct * 16 + kg * 4;
            const int sres = (c0 + ct * 16) >> 6;
            const float4 bo4 = *(const float4*)(bo + g * D + cb);
            #pragma unroll
            for (int rt = 0; rt < 4; rt++) {
                const int r = rt * 16 + ar;
                int node = idx_g[min(r, valid - 1) * A + sres];
                bf16x4 xv = *(const bf16x4*)(emb + (long)node * 64 + (cb & 63));
                f32x4 o;
                o[0] = acc[rt][ct][0] + bo4.x + b2f(xv[0]);
                o[1] = acc[rt][ct][1] + bo4.y + b2f(xv[1]);
                o[2] = acc[rt][ct][2] + bo4.z + b2f(xv[2]);
                o[3] = acc[rt][ct][3] + bo4.w + b2f(xv[3]);
                if (r < valid)
                    __builtin_nontemporal_store(o, (f32x4*)(ob + (long)r * D + cb));
            }
        }
    }
}

struct KArgs {
    const __hip_bfloat16* emb;
    const int* idx[4];
    const __hip_bfloat16* wi[4]; const float* bi[4];
    const __hip_bfloat16* wo[4]; const float* bo[4];
    float* om[4]; float* oi[4];
};

// Single merged kernel: contiguous group ranges (D=256 first, then 192, 128, 64).
// LDS 34816B: holds D=256 single region (64x264x2=33792) OR two D<=128 regions
// (2x64x136x2=34816). 4 blocks/CU -> 139KB of 160KB.
__global__ __launch_bounds__(256, 4)
void fused_kernel(KArgs a) {
    __shared__ __hip_bfloat16 buf[2 * TM * 136];
    const int b = blockIdx.x;
    if (b < NB) {
        body<256, 4, 2>(b, 0, a.emb, a.idx[3], a.wi[3], a.bi[3], a.wo[3], a.bo[3], a.om[3], a.oi[3], buf);
    } else if (b < NB * 3) {
        int r = b - NB;
        body<192, 3, 1>(r % NB, r / NB, a.emb, a.idx[2], a.wi[2], a.bi[2], a.wo[2], a.bo[2], a.om[2], a.oi[2], buf);
    } else if (b < NB * 6) {
        int r = b - NB * 3;
        body<128, 2, 0>(r % NB, r / NB, a.emb, a.idx[1], a.wi[1], a.bi[1], a.wo[1], a.bo[1], a.om[1], a.oi[1], buf);
    } else {
        int r = b - NB * 6;
        body<64, 1, 0>(r % NB, r / NB, a.emb, a.idx[0], a.wi[0], a.bi[0], a.wo[0], a.bo[0], a.om[0], a.oi[0], buf);
    }
}

// ---- fallback (ws too small): on-the-fly f32 path, row-major weights ----
template<int D, int A, int MINW>
__global__ __launch_bounds__(256, MINW)
void msg_kernel(const float* __restrict__ embv,
                const int* __restrict__ idx,
                const float* __restrict__ wiv, const float* __restrict__ bi,
                const float* __restrict__ wov, const float* __restrict__ bo,
                float* __restrict__ out_msgs, float* __restrict__ out_idx)
{
    constexpr int DP = D + 8;
    constexpr int CT = D / 64;
    constexpr int KS = D / 32;
    constexpr int RC = D / 8;
    __shared__ __hip_bfloat16 buf[TM][DP];

    const int g    = blockIdx.y;
    const int f0   = blockIdx.x * TM;
    const int tid  = threadIdx.x;
    const int lane = tid & 63;
    const int w    = tid >> 6;
    const long gFA = (long)g * NF * A;
    const int valid = min(TM, NF - f0);

    {
        const int* idx_g = idx + gFA + (long)f0 * A;
        #pragma unroll
        for (int c = tid; c < TM * RC; c += 256) {
            int r = c / RC;
            int i = (c - r * RC) * 8;
            bf16x8 v = (bf16x8)0;
            if (r < valid) {
                int node = idx_g[r * A + (i >> 6)];
                const float4* s = (const float4*)(embv + (long)node * 64 + (i & 63));
                v = cvt8(s[0], s[1]);
            }
            *(bf16x8*)(&buf[r][i]) = v;
        }
        if (tid < valid * A) out_idx[gFA + (long)f0 * A + tid] = (float)idx_g[tid];
    }
    __syncthreads();

    const int ar = lane & 15;
    const int kg = lane >> 4;
    const int c0 = w * (D / 4);
    const long wbase = (long)g * D * D;

    f32x4 acc[4][CT];
    #pragma unroll
    for (int rt = 0; rt < 4; rt++)
        #pragma unroll
        for (int ct = 0; ct < CT; ct++) acc[rt][ct] = (f32x4)0.0f;

    #pragma unroll
    for (int ks = 0; ks < KS; ks++) {
        const int kk = ks * 32;
        bf16x8 xb[4];
        #pragma unroll
        for (int rt = 0; rt < 4; rt++) xb[rt] = *(const bf16x8*)(&buf[rt * 16 + ar][kk + kg * 8]);
        #pragma unroll
        for (int ct = 0; ct < CT; ct++) {
            const float4* bp = (const float4*)(wiv + wbase + (long)(c0 + ct * 16 + ar) * D + kk + kg * 8);
            bf16x8 wf = cvt8(bp[0], bp[1]);
            #pragma unroll
            for (int rt = 0; rt < 4; rt++)
                acc[rt][ct] = __builtin_amdgcn_mfma_f32_16x16x32_bf16(wf, xb[rt], acc[rt][ct], 0, 0, 0);
        }
    }

    bf16x4 res[4][CT];
    #pragma unroll
    for (int ct = 0; ct < CT; ct++) {
        const int cb = c0 + ct * 16 + kg * 4;
        #pragma unroll
        for (int rt = 0; rt < 4; rt++)
            res[rt][ct] = *(const bf16x4*)(&buf[rt * 16 + ar][cb]);
    }
    __syncthreads();

    #pragma unroll
    for (int ct = 0; ct < CT; ct++) {
        const int cb = c0 + ct * 16 + kg * 4;
        const float4 bi4 = *(const float4*)(bi + g * D + cb);
        #pragma unroll
        for (int rt = 0; rt < 4; rt++) {
            bf16x4 hv;
            hv[0] = bfs(mish_f(acc[rt][ct][0] + bi4.x));
            hv[1] = bfs(mish_f(acc[rt][ct][1] + bi4.y));
            hv[2] = bfs(mish_f(acc[rt][ct][2] + bi4.z));
            hv[3] = bfs(mish_f(acc[rt][ct][3] + bi4.w));
            *(bf16x4*)(&buf[rt * 16 + ar][cb]) = hv;
        }
    }
    __syncthreads();

    #pragma unroll
    for (int rt = 0; rt < 4; rt++)
        #pragma unroll
        for (int ct = 0; ct < CT; ct++) acc[rt][ct] = (f32x4)0.0f;

    #pragma unroll
    for (int ks = 0; ks < KS; ks++) {
        const int kk = ks * 32;
        bf16x8 hb[4];
        #pragma unroll
        for (int rt = 0; rt < 4; rt++) hb[rt] = *(const bf16x8*)(&buf[rt * 16 + ar][kk + kg * 8]);
        #pragma unroll
        for (int ct = 0; ct < CT; ct++) {
            const float4* bp = (const float4*)(wov + wbase + (long)(c0 + ct * 16 + ar) * D + kk + kg * 8);
            bf16x8 wf = cvt8(bp[0], bp[1]);
            #pragma unroll
            for (int rt = 0; rt < 4; rt++)
                acc[rt][ct] = __builtin_amdgcn_mfma_f32_16x16x32_bf16(wf, hb[rt], acc[rt][ct], 0, 0, 0);
        }
    }

    {
        float* ob = out_msgs + (gFA + (long)f0 * A) * 64;
        #pragma unroll
        for (int ct = 0; ct < CT; ct++) {
            const int cb = c0 + ct * 16 + kg * 4;
            const float4 bo4 = *(const float4*)(bo + g * D + cb);
            #pragma unroll
            for (int rt = 0; rt < 4; rt++) {
                const int r = rt * 16 + ar;
                float4 o;
                o.x = acc[rt][ct][0] + bo4.x + b2f(res[rt][ct][0]);
                o.y = acc[rt][ct][1] + bo4.y + b2f(res[rt][ct][1]);
                o.z = acc[rt][ct][2] + bo4.z + b2f(res[rt][ct][2]);
                o.w = acc[rt][ct][3] + bo4.w + b2f(res[rt][ct][3]);
                if (r < valid) *(float4*)(ob + (long)r * D + cb) = o;
            }
        }
    }
}

extern "C" void kernel_launch(void* const* d_in, const int* in_sizes, int n_in,
                              void* d_out, int out_size, void* d_ws, size_t ws_size,
                              hipStream_t stream) {
    const float* emb_f = (const float*)d_in[0];
    const int Gs[4] = {2, 3, 2, 1};
    const int Ds[4] = {64, 128, 192, 256};

    const int*   idx_a[4];
    const float *wi_f[4], *bi_f[4], *wo_f[4], *bo_f[4];
    for (int k = 0; k < 4; k++) {
        idx_a[k] = (const int*)d_in[1 + 5 * k];
        wi_f[k]  = (const float*)d_in[2 + 5 * k];
        bi_f[k]  = (const float*)d_in[3 + 5 * k];
        wo_f[k]  = (const float*)d_in[4 + 5 * k];
        bo_f[k]  = (const float*)d_in[5 + 5 * k];
    }

    float* out = (float*)d_out;
    const long MSG_ELEMS = 115200000L;
    const long rowOff[4] = {0, 200000, 800000, 1400000};
    float* om[4]; float* oi[4];
    for (int k = 0; k < 4; k++) {
        om[k] = out + rowOff[k] * 64;
        oi[k] = out + MSG_ELEMS + rowOff[k];
    }

    const long EMB_ELEMS = 6400000L;
    long wPre[9]; wPre[0] = 0;
    int  wD[8];
    for (int k = 0; k < 4; k++) {
        long we = (long)Gs[k] * Ds[k] * Ds[k];
        wPre[2 * k + 1] = wPre[2 * k] + we;
        wPre[2 * k + 2] = wPre[2 * k + 1] + we;
        wD[2 * k] = Ds[k]; wD[2 * k + 1] = Ds[k];
    }
    const long NEED = (EMB_ELEMS + wPre[8]) * 2;

    if (ws_size >= (size_t)NEED) {
        __hip_bfloat16* emb_b = (__hip_bfloat16*)d_ws;
        __hip_bfloat16* w_b   = emb_b + EMB_ELEMS;

        CvtA ca;
        for (int k = 0; k < 4; k++) { ca.src[2 * k] = wi_f[k]; ca.src[2 * k + 1] = wo_f[k]; }
        for (int j = 0; j < 9; j++) ca.pre[j] = wPre[j];
        for (int j = 0; j < 8; j++) ca.Dv[j] = wD[j];
        ca.emb = emb_f;
        ca.embElems = EMB_ELEMS;
        long totChunks = (EMB_ELEMS + wPre[8]) / 8;
        cvt_all<<<dim3((totChunks + 255) / 256), dim3(256), 0, stream>>>(ca, emb_b);

        KArgs a;
        a.emb = emb_b;
        for (int k = 0; k < 4; k++) {
            a.idx[k] = idx_a[k];
            a.wi[k] = w_b + wPre[2 * k];
            a.wo[k] = w_b + wPre[2 * k + 1];
            a.bi[k] = bi_f[k];
            a.bo[k] = bo_f[k];
            a.om[k] = om[k];
            a.oi[k] = oi[k];
        }
        fused_kernel<<<dim3(NB * 8), dim3(256), 0, stream>>>(a);
    } else {
        msg_kernel<64, 1, 4><<<dim3(NB, 2), 256, 0, stream>>>(
            emb_f, idx_a[0], wi_f[0], bi_f[0], wo_f[0], bo_f[0], om[0], oi[0]);
        msg_kernel<128, 2, 4><<<dim3(NB, 3), 256, 0, stream>>>(
            emb_f, idx_a[1], wi_f[1], bi_f[1], wo_f[1], bo_f[1], om[1], oi[1]);
        msg_kernel<192, 3, 4><<<dim3(NB, 2), 256, 0, stream>>>(
            emb_f, idx_a[2], wi_f[2], bi_f[2], wo_f[2], bo_f[2], om[2], oi[2]);
        msg_kernel<256, 4, 3><<<dim3(NB, 1), 256, 0, stream>>>(
            emb_f, idx_a[3], wi_f[3], bi_f[3], wo_f[3], bo_f[3], om[3], oi[3]);
    }
}